// Round 16
// baseline (14839.891 us; speedup 1.0000x reference)
//
#include <hip/hip_runtime.h>
#include <stdint.h>
#include <stddef.h>

typedef __bf16 bf16;
typedef __bf16 bf16x8 __attribute__((ext_vector_type(8)));
typedef __bf16 bf16x4 __attribute__((ext_vector_type(4)));
typedef float  f32x4  __attribute__((ext_vector_type(4)));

#define B_ 8
#define T_ 2048
#define D_ 1024
#define L_ 2

#define AS1C(p) ((const __attribute__((address_space(1))) void*)(p))
#define AS3(p)  ((__attribute__((address_space(3))) void*)(p))

// Compact bf16 frame (16384 B): byte(b,n) = (n>>5)*512 + (((n&31)>>3)*8+b)*16 + (n&7)*2
// uv planes (bf16): plane p (0=u,1=v) elem(t,n',b) at p*T*8192 + t*8192 + n'*8 + b
// sync dword offsets: S1 packed per-wave [0..63] | S2 padded 128+wg*16 (8)
//   S3 padded 256+wg*16 (16) | S4 packed per-wave [512..575]
// slot value = t+1 after step t published.

// ---------------- f32 -> bf16 convert ----------------
__global__ __launch_bounds__(256) void cvt_kernel(const float* __restrict__ in,
                                                  bf16* __restrict__ out, int n4) {
  int i = blockIdx.x * 256 + threadIdx.x;
  if (i >= n4) return;
  float4 v = ((const float4*)in)[i];
  bf16x4 o = { (bf16)v.x, (bf16)v.y, (bf16)v.z, (bf16)v.w };
  ((bf16x4*)out)[i] = o;
}

// ---------------- LayerNorm (layer 1 bulk) ----------------
__global__ __launch_bounds__(256) void ln_kernel(const float* __restrict__ x,
                                                 const float* __restrict__ g,
                                                 const float* __restrict__ b,
                                                 bf16* __restrict__ xn) {
  const int row = blockIdx.x;
  const int tid = threadIdx.x;
  const float4 v = ((const float4*)(x + (size_t)row * D_))[tid];
  float s1 = v.x + v.y + v.z + v.w;
  float s2 = v.x * v.x + v.y * v.y + v.z * v.z + v.w * v.w;
#pragma unroll
  for (int off = 1; off < 64; off <<= 1) {
    s1 += __shfl_xor(s1, off);
    s2 += __shfl_xor(s2, off);
  }
  __shared__ float r1[4], r2[4];
  if ((tid & 63) == 0) { r1[tid >> 6] = s1; r2[tid >> 6] = s2; }
  __syncthreads();
  s1 = r1[0] + r1[1] + r1[2] + r1[3];
  s2 = r2[0] + r2[1] + r2[2] + r2[3];
  const float mu = s1 * (1.f / D_);
  const float var = s2 * (1.f / D_) - mu * mu;
  const float rs = rsqrtf(var + 1e-5f);
  const float4 gv = ((const float4*)g)[tid];
  const float4 bv = ((const float4*)b)[tid];
  bf16x4 o = { (bf16)((v.x - mu) * rs * gv.x + bv.x),
               (bf16)((v.y - mu) * rs * gv.y + bv.y),
               (bf16)((v.z - mu) * rs * gv.z + bv.z),
               (bf16)((v.w - mu) * rs * gv.w + bv.w) };
  ((bf16x4*)(xn + (size_t)row * D_))[tid] = o;
}

// ---- layer-2 fold precompute ----
__global__ __launch_bounds__(256) void prep2_kernel(const float* __restrict__ Win2,
    const float* __restrict__ g2, const float* __restrict__ be2,
    const float* __restrict__ bin2, bf16* __restrict__ W2p,
    float* __restrict__ csum, float* __restrict__ cbias) {
  const int n = blockIdx.x;
  const int tid = threadIdx.x;
  const float4 w4 = ((const float4*)(Win2 + (size_t)n * 1024))[tid];
  const float4 g4 = ((const float4*)g2)[tid];
  const float4 b4 = ((const float4*)be2)[tid];
  bf16x4 o = { (bf16)(g4.x * w4.x), (bf16)(g4.y * w4.y),
               (bf16)(g4.z * w4.z), (bf16)(g4.w * w4.w) };
  ((bf16x4*)(W2p + (size_t)n * 1024))[tid] = o;
  float s = (float)o[0] + (float)o[1] + (float)o[2] + (float)o[3];
  float cbv = b4.x * w4.x + b4.y * w4.y + b4.z * w4.z + b4.w * w4.w;
#pragma unroll
  for (int off = 1; off < 64; off <<= 1) {
    s += __shfl_xor(s, off);
    cbv += __shfl_xor(cbv, off);
  }
  __shared__ float rs_[4], rc_[4];
  if ((tid & 63) == 0) { rs_[tid >> 6] = s; rc_[tid >> 6] = cbv; }
  __syncthreads();
  if (tid == 0) {
    csum[n] = rs_[0] + rs_[1] + rs_[2] + rs_[3];
    cbias[n] = rc_[0] + rc_[1] + rc_[2] + rc_[3] + bin2[n];
  }
}

// ---- in_proj GEMM (layer 1): writes bf16 uv PLANES ----
__global__ __launch_bounds__(256) void gemm_uv(const bf16* __restrict__ A,
                                               const bf16* __restrict__ Bw,
                                               const float* __restrict__ bias,
                                               bf16* __restrict__ uvp,
                                               int M, int N, int K) {
  __shared__ bf16 As[128 * 32];
  __shared__ bf16 Bs[128 * 32];
  const int tid = threadIdx.x;
  const int lane = tid & 63;
  const int wave = tid >> 6;
  const int m0 = blockIdx.y * 128;
  const int n0 = blockIdx.x * 128;
  const int wm = (wave >> 1) * 64;
  const int wn = (wave & 1) * 64;
  f32x4 acc[4][4] = {};

  for (int kt = 0; kt < K; kt += 32) {
#pragma unroll
    for (int it = 0; it < 2; ++it) {
      const int gidx = it * 256 + tid;
      const int row = gidx >> 2;
      const int col = (gidx & 3) << 3;
      __builtin_amdgcn_global_load_lds(AS1C(A + (size_t)(m0 + row) * K + kt + col),
                                       AS3(&As[gidx * 8]), 16, 0, 0);
      __builtin_amdgcn_global_load_lds(AS1C(Bw + (size_t)(n0 + row) * K + kt + col),
                                       AS3(&Bs[gidx * 8]), 16, 0, 0);
    }
    __syncthreads();
    bf16x8 af[4], bfr[4];
#pragma unroll
    for (int i = 0; i < 4; ++i)
      af[i] = *(const bf16x8*)&As[(wm + i * 16 + (lane & 15)) * 32 + (lane >> 4) * 8];
#pragma unroll
    for (int j = 0; j < 4; ++j)
      bfr[j] = *(const bf16x8*)&Bs[(wn + j * 16 + (lane & 15)) * 32 + (lane >> 4) * 8];
#pragma unroll
    for (int i = 0; i < 4; ++i)
#pragma unroll
      for (int j = 0; j < 4; ++j)
        acc[i][j] = __builtin_amdgcn_mfma_f32_16x16x32_bf16(af[i], bfr[j], acc[i][j], 0, 0, 0);
    __syncthreads();
  }

  const int cr = (lane >> 4) * 4;
  const int cc = lane & 15;
#pragma unroll
  for (int i = 0; i < 4; ++i) {
#pragma unroll
    for (int j = 0; j < 4; ++j) {
      const int mb = m0 + wm + i * 16 + cr;
      const int n = n0 + wn + j * 16 + cc;
      const float bn = bias[n];
      const int p = n >> 10;
      const int nn2 = n & 1023;
#pragma unroll
      for (int r = 0; r < 4; ++r) {
        const int row = mb + r;
        const int b = row >> 11;
        const int t = row & (T_ - 1);
        uvp[(size_t)p * T_ * 8192 + (size_t)t * 8192 + nn2 * 8 + b] =
            (bf16)(acc[i][j][r] + bn);
      }
    }
  }
}

// ---- final out_proj GEMM (layer 2) ----
__global__ __launch_bounds__(256) void gemm_hfrag(const char* __restrict__ Hb,
                                                  const bf16* __restrict__ Bw,
                                                  const float* __restrict__ bias,
                                                  const char* __restrict__ residF,
                                                  float* __restrict__ C,
                                                  int M, int N, int K) {
  __shared__ bf16 As[128 * 32];
  __shared__ bf16 Bs[128 * 32];
  const int tid = threadIdx.x;
  const int lane = tid & 63;
  const int wave = tid >> 6;
  const int m0 = blockIdx.y * 128;
  const int n0 = blockIdx.x * 128;
  const int wm = (wave >> 1) * 64;
  const int wn = (wave & 1) * 64;
  f32x4 acc[4][4] = {};

  for (int kt = 0; kt < K; kt += 32) {
#pragma unroll
    for (int it = 0; it < 2; ++it) {
      const int g = it * 256 + tid;
      const int r = g >> 2;
      const int sub = g & 3;
      const int R = m0 + r;
      const int bb = R >> 11;
      const int tt = R & (T_ - 1);
      const char* src = Hb + (size_t)tt * 16384 + (size_t)(kt >> 5) * 512
                        + (sub * 8 + bb) * 16;
      __builtin_amdgcn_global_load_lds(AS1C(src), AS3(&As[g * 8]), 16, 0, 0);
      __builtin_amdgcn_global_load_lds(AS1C(Bw + (size_t)(n0 + r) * K + kt + (sub << 3)),
                                       AS3(&Bs[g * 8]), 16, 0, 0);
    }
    __syncthreads();
    bf16x8 af[4], bfr[4];
#pragma unroll
    for (int i = 0; i < 4; ++i)
      af[i] = *(const bf16x8*)&As[(wm + i * 16 + (lane & 15)) * 32 + (lane >> 4) * 8];
#pragma unroll
    for (int j = 0; j < 4; ++j)
      bfr[j] = *(const bf16x8*)&Bs[(wn + j * 16 + (lane & 15)) * 32 + (lane >> 4) * 8];
#pragma unroll
    for (int i = 0; i < 4; ++i)
#pragma unroll
      for (int j = 0; j < 4; ++j)
        acc[i][j] = __builtin_amdgcn_mfma_f32_16x16x32_bf16(af[i], bfr[j], acc[i][j], 0, 0, 0);
    __syncthreads();
  }

  const int cr = (lane >> 4) * 4;
  const int cc = lane & 15;
#pragma unroll
  for (int i = 0; i < 4; ++i) {
#pragma unroll
    for (int j = 0; j < 4; ++j) {
      const int mb = m0 + wm + i * 16 + cr;
      const int n = n0 + wn + j * 16 + cc;
      const float bn = bias[n];
      const int foffn = (n >> 5) * 512 + (((n & 31) >> 3) * 8) * 16 + (n & 7) * 2;
#pragma unroll
      for (int r = 0; r < 4; ++r) {
        const int row = mb + r;
        const int b = row >> 11;
        const int tt2 = row & (T_ - 1);
        const float resid =
            (float)*(const bf16*)(residF + (size_t)tt2 * 16384 + foffn + b * 16);
        C[(size_t)row * N + n] = acc[i][j][r] + bn + resid;
      }
    }
  }
}

// ================= mega persistent pipeline =================
__device__ __forceinline__ void load_wb(bf16x8 (&wB)[32], const bf16* Wrow) {
  const int half = ((threadIdx.x & 63) >> 4) << 3;
#pragma unroll
  for (int kk = 0; kk < 32; ++kk)
    wB[kk] = *(const bf16x8*)(Wrow + kk * 32 + half);
#pragma unroll
  for (int kk = 0; kk < 32; ++kk)
    asm volatile("" : "+a"(wB[kk]));  // park in AGPRs
}

__device__ __forceinline__ f32x4 frag_matvec(const char* __restrict__ dF, int rdoff,
                                             const bf16x8 (&wB)[32]) {
  f32x4 a0 = {0.f, 0.f, 0.f, 0.f}, a1 = a0, a2 = a0, a3 = a0;
#pragma unroll
  for (int kk = 0; kk < 32; kk += 4) {
    bf16x8 f0 = *(const bf16x8*)(dF + kk * 512 + rdoff);
    bf16x8 f1 = *(const bf16x8*)(dF + (kk + 1) * 512 + rdoff);
    bf16x8 f2 = *(const bf16x8*)(dF + (kk + 2) * 512 + rdoff);
    bf16x8 f3 = *(const bf16x8*)(dF + (kk + 3) * 512 + rdoff);
    a0 = __builtin_amdgcn_mfma_f32_16x16x32_bf16(f0, wB[kk], a0, 0, 0, 0);
    a1 = __builtin_amdgcn_mfma_f32_16x16x32_bf16(f1, wB[kk + 1], a1, 0, 0, 0);
    a2 = __builtin_amdgcn_mfma_f32_16x16x32_bf16(f2, wB[kk + 2], a2, 0, 0, 0);
    a3 = __builtin_amdgcn_mfma_f32_16x16x32_bf16(f3, wB[kk + 3], a3, 0, 0, 0);
  }
  return (a0 + a1) + (a2 + a3);
}

// 64 packed slots; called by ALL waves (each verifies independently).
template <int SLP>
__device__ __forceinline__ void poll64(const unsigned* base, unsigned tgt) {
  const int lane = threadIdx.x & 63;
  unsigned sv = __hip_atomic_load(base + lane, __ATOMIC_RELAXED, __HIP_MEMORY_SCOPE_AGENT);
  while (!__all((int)(sv >= tgt))) {
    __builtin_amdgcn_s_sleep(SLP);
    sv = __hip_atomic_load(base + lane, __ATOMIC_RELAXED, __HIP_MEMORY_SCOPE_AGENT);
  }
  (void)__hip_atomic_load(base, __ATOMIC_ACQUIRE, __HIP_MEMORY_SCOPE_AGENT);
}

// 8 padded slots (64B apart); called by ALL waves.
template <int SLP>
__device__ __forceinline__ void poll8p(const unsigned* base, unsigned tgt) {
  const int lane = threadIdx.x & 63;
  unsigned sv = tgt;
  if (lane < 8)
    sv = __hip_atomic_load(base + lane * 16, __ATOMIC_RELAXED, __HIP_MEMORY_SCOPE_AGENT);
  while (!__all((int)(sv >= tgt))) {
    __builtin_amdgcn_s_sleep(SLP);
    if (lane < 8)
      sv = __hip_atomic_load(base + lane * 16, __ATOMIC_RELAXED, __HIP_MEMORY_SCOPE_AGENT);
  }
  (void)__hip_atomic_load(base, __ATOMIC_ACQUIRE, __HIP_MEMORY_SCOPE_AGENT);
}

// S4 gate: the 2 S3 slots feeding this gang's columns; called by ALL waves.
__device__ __forceinline__ void poll2s3(const unsigned* sync, int wg, unsigned tgt) {
  const int lane = threadIdx.x & 63;
  unsigned sv = tgt;
  if (lane < 2)
    sv = __hip_atomic_load(sync + 256 + ((lane ? 8 : 0) + wg) * 16,
                           __ATOMIC_RELAXED, __HIP_MEMORY_SCOPE_AGENT);
  while (!__all((int)(sv >= tgt))) {
    __builtin_amdgcn_s_sleep(1);
    if (lane < 2)
      sv = __hip_atomic_load(sync + 256 + ((lane ? 8 : 0) + wg) * 16,
                             __ATOMIC_RELAXED, __HIP_MEMORY_SCOPE_AGENT);
  }
  (void)__hip_atomic_load(sync + 256, __ATOMIC_ACQUIRE, __HIP_MEMORY_SCOPE_AGENT);
}

__device__ __forceinline__ void stage16k(const char* srcF, char* dstF, int tid) {
  __builtin_amdgcn_global_load_lds(AS1C(srcF + tid * 16), AS3(dstF + tid * 16), 16, 0, 0);
  __builtin_amdgcn_global_load_lds(AS1C(srcF + (512 + tid) * 16),
                                   AS3(dstF + (512 + tid) * 16), 16, 0, 0);
}

// Scans (r14 structure + r8's per-wave packed release + amortized gate):
// all waves poll 64 packed slots; per-wave release right after publish (no WG
// barrier); GATED: S3 gate checked at t%8==1 demanding min(t+15,T) — strictly
// stronger than r14's every-step t+8 guarantee, 1/8 the gate-line traffic.
template <bool GATED>
__device__ __forceinline__ void scan_gang(int wg, const bf16* uvU, const bf16* uvV,
    const bf16* Wh, const float* bh, char* Hb, unsigned* sync, int ownBase,
    char (*hC)[16384], char (*tscr)[256]) {
  const int tid = threadIdx.x;
  const int lane = tid & 63;
  const int wv = tid >> 6;
  const int Wg = wg * 8 + wv;
  const int n0 = Wg * 16;
  const int c = lane & 15;

  bf16x8 wB[32];
  load_wb(wB, Wh + ((size_t)(n0 + c) << 10));

  const float bh_n = bh[n0 + c];
  const int b0 = (lane >> 4) * 4;
  const int rdoff = ((lane >> 4) * 8 + (lane & 7)) * 16;
  const int wregion = Wg * 256;

  float hs0 = 0.f, hs1 = 0.f, hs2 = 0.f, hs3 = 0.f;
  bf16x4 uq = {}, vq = {};

  // initial gate (S3 >= 16 steps done) + uv[0] prefetch
  if (GATED) poll2s3(sync, wg, (unsigned)(16 < T_ ? 16 : T_));
  if (lane < 32) {
    uq = *(const bf16x4*)(uvU + (n0 + c) * 8 + b0);
    vq = *(const bf16x4*)(uvV + (n0 + c) * 8 + b0);
  }

  for (int t = 0; t < T_; ++t) {
    f32x4 asum = {0.f, 0.f, 0.f, 0.f};
    if (t > 0) {
      poll64<1>(sync + ownBase, (unsigned)t);
      __builtin_amdgcn_sched_barrier(0);
      stage16k(Hb + (size_t)(t - 1) * 16384, hC[t & 1], tid);
      if (GATED && (t & 7) == 1)
        poll2s3(sync, wg, (unsigned)((t + 15 < T_) ? t + 15 : T_));
      __syncthreads();
      asum = frag_matvec(hC[t & 1], rdoff, wB);
    }

    char* wscr = tscr[wv];
    if (lane < 32) {
#pragma unroll
      for (int r = 0; r < 4; ++r) {
        const float uu = (float)uq[r];
        const float vv = (float)vq[r];
        float& hh = (r == 0) ? hs0 : (r == 1) ? hs1 : (r == 2) ? hs2 : hs3;
        const float s = asum[r] + bh_n + vv;
        const float gg = __builtin_amdgcn_rcpf(1.f + __expf(-uu));
        const float e = __expf(2.f * s);
        const float cand = 1.f - 2.f * __builtin_amdgcn_rcpf(e + 1.f);
        hh = fmaf(gg, cand - hh, hh);
        *(bf16*)(wscr + (c >> 3) * 128 + (b0 + r) * 16 + (c & 7) * 2) = (bf16)hh;
      }
    }
    asm volatile("s_waitcnt lgkmcnt(0)" ::: "memory");
    __builtin_amdgcn_sched_barrier(0);
    if (lane < 32) {
      const unsigned long long pv = *(const unsigned long long*)(wscr + lane * 8);
      char* dst = Hb + (size_t)t * 16384 + wregion + lane * 8;
      __hip_atomic_store((unsigned long long*)dst, pv,
                         __ATOMIC_RELAXED, __HIP_MEMORY_SCOPE_AGENT);
    }
    // per-wave release: drains this wave's publish stores (r8-proven)
    if (lane == 0)
      __hip_atomic_store(sync + ownBase + Wg, (unsigned)(t + 1),
                         __ATOMIC_RELEASE, __HIP_MEMORY_SCOPE_AGENT);
    __builtin_amdgcn_sched_barrier(0);
    // uv prefetch for t+1, post-release (gate guarantee covers GATED reads)
    if (t < T_ - 1 && lane < 32) {
      uq = *(const bf16x4*)(uvU + (size_t)(t + 1) * 8192 + (n0 + c) * 8 + b0);
      vq = *(const bf16x4*)(uvV + (size_t)(t + 1) * 8192 + (n0 + c) * 8 + b0);
    }
  }
}

// S2: out1[t] = x[t] + h1[t] @ Wout1^T + bout1  (pipelined stage, no recurrence)
__device__ __forceinline__ void s2_gang(int wg, const char* H1, const bf16* Wout,
    const float* bout, const float* x, char* out1F, unsigned* sync,
    char (*hC)[16384], char (*tscr)[256]) {
  const int tid = threadIdx.x;
  const int lane = tid & 63;
  const int wv = tid >> 6;
  const int W2 = wg * 8 + wv;
  const int n0 = W2 * 16;
  const int c = lane & 15;

  bf16x8 wB[32];
  load_wb(wB, Wout + ((size_t)(n0 + c) << 10));

  const float bo = bout[n0 + c];
  const int b0 = (lane >> 4) * 4;
  const int rdoff = ((lane >> 4) * 8 + (lane & 7)) * 16;
  const int wregion = W2 * 256;

  f32x4 xq = {0.f, 0.f, 0.f, 0.f};
  if (lane < 32) {
#pragma unroll
    for (int r = 0; r < 4; ++r)
      xq[r] = x[((size_t)(b0 + r) * T_) * 1024 + n0 + c];
  }

  poll64<4>(sync, 1u);
  __builtin_amdgcn_sched_barrier(0);
  stage16k(H1, hC[0], tid);

  for (int t = 0; t < T_; ++t) {
    __syncthreads();  // stage t complete
    f32x4 asum = frag_matvec(hC[t & 1], rdoff, wB);

    char* wscr = tscr[wv];
    if (lane < 32) {
#pragma unroll
      for (int r = 0; r < 4; ++r) {
        const float o = xq[r] + asum[r] + bo;
        *(bf16*)(wscr + (c >> 3) * 128 + (b0 + r) * 16 + (c & 7) * 2) = (bf16)o;
      }
    }
    asm volatile("s_waitcnt lgkmcnt(0)" ::: "memory");
    __builtin_amdgcn_sched_barrier(0);
    if (lane < 32) {
      const unsigned long long pv = *(const unsigned long long*)(wscr + lane * 8);
      char* dst = out1F + (size_t)t * 16384 + wregion + lane * 8;
      __hip_atomic_store((unsigned long long*)dst, pv,
                         __ATOMIC_RELAXED, __HIP_MEMORY_SCOPE_AGENT);
    }
    __syncthreads();
    if (tid == 0)
      __hip_atomic_store(sync + 128 + wg * 16, (unsigned)(t + 1),
                         __ATOMIC_RELEASE, __HIP_MEMORY_SCOPE_AGENT);
    __builtin_amdgcn_sched_barrier(0);
    if (t + 1 < T_) {
      poll64<4>(sync, (unsigned)(t + 2));
      __builtin_amdgcn_sched_barrier(0);
      stage16k(H1 + (size_t)(t + 1) * 16384, hC[(t + 1) & 1], tid);
      if (lane < 32) {
#pragma unroll
        for (int r = 0; r < 4; ++r)
          xq[r] = x[((size_t)(b0 + r) * T_ + (t + 1)) * 1024 + n0 + c];
      }
    }
  }
}

// S3: uv2[t] = folded-LN(out1[t]) @ W2p^T  (pipelined stage + conflict-free stats)
__device__ __forceinline__ void s3_gang(int wg, const char* out1F, const bf16* W2p,
    const float* csum2, const float* cbias2, bf16* uv2, unsigned* sync,
    char (*hC)[16384], char (*tscr)[256], float* statp) {
  const int tid = threadIdx.x;
  const int lane = tid & 63;
  const int wv = tid >> 6;
  const int W3 = wg * 8 + wv;              // 0..127
  const int c = lane & 15;
  const int n = W3 * 16 + c;               // col in [0,2048)

  bf16x8 wB[32];
  load_wb(wB, W2p + ((size_t)n << 10));

  const float cs = csum2[n];
  const float cb = cbias2[n];
  const int b0 = (lane >> 4) * 4;
  const int rdoff = ((lane >> 4) * 8 + (lane & 7)) * 16;
  char* outPlane = (char*)(uv2 + (size_t)(W3 >> 6) * T_ * 8192);
  const int nn = (W3 & 63) * 16;
  const int sidx = wv * 128 + lane;        // contiguous 16B block index

  poll8p<4>(sync + 128, 1u);
  __builtin_amdgcn_sched_barrier(0);
  stage16k(out1F, hC[0], tid);

  for (int t = 0; t < T_; ++t) {
    __syncthreads();  // stage t complete
    const char* dstF = hC[t & 1];
    // LN stats partials: contiguous reads (conflict-free); block%8 == batch
    {
      bf16x8 v0 = *(const bf16x8*)(dstF + sidx * 16);
      bf16x8 v1 = *(const bf16x8*)(dstF + sidx * 16 + 1024);
      float s1 = 0.f, s2 = 0.f;
#pragma unroll
      for (int j = 0; j < 8; ++j) {
        const float f0 = (float)v0[j], f1 = (float)v1[j];
        s1 += f0 + f1;
        s2 += f0 * f0 + f1 * f1;
      }
#pragma unroll
      for (int off = 8; off < 64; off <<= 1) {
        s1 += __shfl_xor(s1, off);
        s2 += __shfl_xor(s2, off);
      }
      if (lane < 8) {
        statp[(wv * 8 + lane) * 2] = s1;
        statp[(wv * 8 + lane) * 2 + 1] = s2;
      }
    }
    f32x4 asum = frag_matvec(dstF, rdoff, wB);
    __syncthreads();  // statp ready
    char* wscr = tscr[wv];
    if (lane < 32) {
#pragma unroll
      for (int r = 0; r < 4; ++r) {
        const int b = b0 + r;
        float s1 = 0.f, s2 = 0.f;
#pragma unroll
        for (int w = 0; w < 8; ++w) {
          s1 += statp[(w * 8 + b) * 2];
          s2 += statp[(w * 8 + b) * 2 + 1];
        }
        const float mu = s1 * (1.f / 1024.f);
        const float var = s2 * (1.f / 1024.f) - mu * mu;
        const float rs = rsqrtf(var + 1e-5f);
        const float val = rs * (asum[r] - mu * cs) + cb;
        *(bf16*)(wscr + c * 16 + b * 2) = (bf16)val;
      }
    }
    asm volatile("s_waitcnt lgkmcnt(0)" ::: "memory");
    __builtin_amdgcn_sched_barrier(0);
    if (lane < 32) {
      const unsigned long long pv = *(const unsigned long long*)(wscr + lane * 8);
      char* dst = outPlane + (size_t)t * 16384 + nn * 16 + lane * 8;
      __hip_atomic_store((unsigned long long*)dst, pv,
                         __ATOMIC_RELAXED, __HIP_MEMORY_SCOPE_AGENT);
    }
    __syncthreads();
    if (tid == 0)
      __hip_atomic_store(sync + 256 + wg * 16, (unsigned)(t + 1),
                         __ATOMIC_RELEASE, __HIP_MEMORY_SCOPE_AGENT);
    __builtin_amdgcn_sched_barrier(0);
    if (t + 1 < T_) {
      poll8p<4>(sync + 128, (unsigned)(t + 2));
      __builtin_amdgcn_sched_barrier(0);
      stage16k(out1F + (size_t)(t + 1) * 16384, hC[(t + 1) & 1], tid);
    }
  }
}

__global__ __launch_bounds__(512, 1) void mega_kernel(
    const bf16* __restrict__ uv1, const bf16* __restrict__ Wh,
    const float* __restrict__ bh, const bf16* __restrict__ Wout,
    const float* __restrict__ bout, const float* __restrict__ x,
    const bf16* __restrict__ W2p, const float* __restrict__ csum2,
    const float* __restrict__ cbias2, char* __restrict__ H1,
    char* __restrict__ out1F, bf16* __restrict__ uv2, char* __restrict__ H2,
    unsigned* __restrict__ sync) {
  __shared__ __align__(16) char hC[2][16384];
  __shared__ __align__(16) char tscr[8][256];
  __shared__ float statp[128];
  const int bid = blockIdx.x;
  if (bid < 8) {
    scan_gang<false>(bid, uv1, uv1 + (size_t)T_ * 8192, Wh, bh, H1, sync, 0, hC, tscr);
  } else if (bid < 16) {
    s2_gang(bid - 8, H1, Wout, bout, x, out1F, sync, hC, tscr);
  } else if (bid < 32) {
    s3_gang(bid - 16, out1F, W2p, csum2, cbias2, uv2, sync, hC, tscr, statp);
  } else {
    scan_gang<true>(bid - 32, uv2, uv2 + (size_t)T_ * 8192,
                    Wh + (size_t)D_ * D_, bh + D_, H2, sync, 512, hC, tscr);
  }
}

extern "C" void kernel_launch(void* const* d_in, const int* in_sizes, int n_in,
                              void* d_out, int out_size, void* d_ws, size_t ws_size,
                              hipStream_t stream) {
  const float* x     = (const float*)d_in[0];
  const float* ln_g  = (const float*)d_in[1];
  const float* ln_b  = (const float*)d_in[2];
  const float* W_in  = (const float*)d_in[3];
  const float* b_in  = (const float*)d_in[4];
  const float* W_h   = (const float*)d_in[5];
  const float* b_h   = (const float*)d_in[6];
  const float* W_out = (const float*)d_in[7];
  const float* b_out = (const float*)d_in[8];
  float* out = (float*)d_out;

  char* ws = (char*)d_ws;
  size_t off = 0;
  auto alloc = [&](size_t bytes) -> void* {
    void* p = ws + off;
    off = (off + bytes + 255) & ~(size_t)255;
    return p;
  };
  bf16* wInB   = (bf16*)alloc((size_t)L_ * 2 * D_ * D_ * 2);   // 8 MB
  bf16* wHB    = (bf16*)alloc((size_t)L_ * D_ * D_ * 2);       // 4 MB
  bf16* wOutB  = (bf16*)alloc((size_t)L_ * D_ * D_ * 2);       // 4 MB
  bf16* W2p    = (bf16*)alloc((size_t)2 * D_ * D_ * 2);        // 4 MB
  float* csum2 = (float*)alloc(2 * D_ * 4);
  float* cbias2= (float*)alloc(2 * D_ * 4);
  bf16* Xn     = (bf16*)alloc((size_t)B_ * T_ * D_ * 2);       // 32 MB (reused as H2)
  char* H2     = (char*)Xn;
  bf16* uvp1   = (bf16*)alloc((size_t)2 * T_ * 8192 * 2);      // 64 MB
  char* H1     = (char*)alloc((size_t)T_ * 16384);             // 32 MB
  char* out1F  = (char*)alloc((size_t)T_ * 16384);             // 32 MB
  bf16* uvp2   = (bf16*)alloc((size_t)2 * T_ * 8192 * 2);      // 64 MB
  unsigned* sync = (unsigned*)alloc(4096);
  (void)ws_size; (void)in_sizes; (void)n_in; (void)out_size;   // ~244 MB used

  {
    int n4 = L_ * 2 * D_ * D_ / 4;
    cvt_kernel<<<(n4 + 255) / 256, 256, 0, stream>>>(W_in, wInB, n4);
    n4 = L_ * D_ * D_ / 4;
    cvt_kernel<<<(n4 + 255) / 256, 256, 0, stream>>>(W_h, wHB, n4);
    cvt_kernel<<<(n4 + 255) / 256, 256, 0, stream>>>(W_out, wOutB, n4);
  }
  prep2_kernel<<<2 * D_, 256, 0, stream>>>(W_in + (size_t)2 * D_ * D_,
                                           ln_g + D_, ln_b + D_, b_in + 2 * D_,
                                           W2p, csum2, cbias2);

  const int Mrows = B_ * T_;  // 16384
  ln_kernel<<<Mrows, 256, 0, stream>>>(x, ln_g, ln_b, Xn);

  dim3 g1(2 * D_ / 128, Mrows / 128);
  gemm_uv<<<g1, 256, 0, stream>>>(Xn, wInB, b_in, uvp1, Mrows, 2 * D_, D_);

  (void)hipMemsetAsync(sync, 0, 4096, stream);
  mega_kernel<<<40, 512, 0, stream>>>(uvp1, wHB, b_h, wOutB, b_out, x,
                                      W2p, csum2, cbias2, H1, out1F, uvp2, H2, sync);

  dim3 g2(D_ / 128, Mrows / 128);
  gemm_hfrag<<<g2, 256, 0, stream>>>(H2, wOutB + (size_t)D_ * D_, b_out + D_,
                                     out1F, out, Mrows, D_, D_);
}

// Round 17
// 9369.917 us; speedup vs baseline: 1.5838x; 1.5838x over previous
//
#include <hip/hip_runtime.h>
#include <stdint.h>
#include <stddef.h>

typedef __bf16 bf16;
typedef __bf16 bf16x8 __attribute__((ext_vector_type(8)));
typedef __bf16 bf16x4 __attribute__((ext_vector_type(4)));
typedef float  f32x4  __attribute__((ext_vector_type(4)));

#define B_ 8
#define T_ 2048
#define D_ 1024
#define L_ 2

#define AS1C(p) ((const __attribute__((address_space(1))) void*)(p))
#define AS3(p)  ((__attribute__((address_space(3))) void*)(p))

// Compact bf16 frame (16384 B): byte(b,n) = (n>>5)*512 + (((n&31)>>3)*8+b)*16 + (n&7)*2
// uv planes (bf16): plane p (0=u,1=v) elem(t,n',b) at p*T*8192 + t*8192 + n'*8 + b
// sync dword offsets (64B-padded slots): S1: 0+wg*16 (8) | S2: 128+wg*16 (8)
//   S3: 256+wg*16 (16) | S4: 512+wg*16 (8).  slot value = t+1 after step t published.

// ---------------- f32 -> bf16 convert ----------------
__global__ __launch_bounds__(256) void cvt_kernel(const float* __restrict__ in,
                                                  bf16* __restrict__ out, int n4) {
  int i = blockIdx.x * 256 + threadIdx.x;
  if (i >= n4) return;
  float4 v = ((const float4*)in)[i];
  bf16x4 o = { (bf16)v.x, (bf16)v.y, (bf16)v.z, (bf16)v.w };
  ((bf16x4*)out)[i] = o;
}

// ---------------- LayerNorm (layer 1 bulk) ----------------
__global__ __launch_bounds__(256) void ln_kernel(const float* __restrict__ x,
                                                 const float* __restrict__ g,
                                                 const float* __restrict__ b,
                                                 bf16* __restrict__ xn) {
  const int row = blockIdx.x;
  const int tid = threadIdx.x;
  const float4 v = ((const float4*)(x + (size_t)row * D_))[tid];
  float s1 = v.x + v.y + v.z + v.w;
  float s2 = v.x * v.x + v.y * v.y + v.z * v.z + v.w * v.w;
#pragma unroll
  for (int off = 1; off < 64; off <<= 1) {
    s1 += __shfl_xor(s1, off);
    s2 += __shfl_xor(s2, off);
  }
  __shared__ float r1[4], r2[4];
  if ((tid & 63) == 0) { r1[tid >> 6] = s1; r2[tid >> 6] = s2; }
  __syncthreads();
  s1 = r1[0] + r1[1] + r1[2] + r1[3];
  s2 = r2[0] + r2[1] + r2[2] + r2[3];
  const float mu = s1 * (1.f / D_);
  const float var = s2 * (1.f / D_) - mu * mu;
  const float rs = rsqrtf(var + 1e-5f);
  const float4 gv = ((const float4*)g)[tid];
  const float4 bv = ((const float4*)b)[tid];
  bf16x4 o = { (bf16)((v.x - mu) * rs * gv.x + bv.x),
               (bf16)((v.y - mu) * rs * gv.y + bv.y),
               (bf16)((v.z - mu) * rs * gv.z + bv.z),
               (bf16)((v.w - mu) * rs * gv.w + bv.w) };
  ((bf16x4*)(xn + (size_t)row * D_))[tid] = o;
}

// ---- layer-2 fold precompute: W2p = g (.) W_in2 (bf16), csum_n = sum_k W2p,
//      cbias_n = sum_k beta_k*W_in2[n][k] + b_in2[n] ----
__global__ __launch_bounds__(256) void prep2_kernel(const float* __restrict__ Win2,
    const float* __restrict__ g2, const float* __restrict__ be2,
    const float* __restrict__ bin2, bf16* __restrict__ W2p,
    float* __restrict__ csum, float* __restrict__ cbias) {
  const int n = blockIdx.x;
  const int tid = threadIdx.x;
  const float4 w4 = ((const float4*)(Win2 + (size_t)n * 1024))[tid];
  const float4 g4 = ((const float4*)g2)[tid];
  const float4 b4 = ((const float4*)be2)[tid];
  bf16x4 o = { (bf16)(g4.x * w4.x), (bf16)(g4.y * w4.y),
               (bf16)(g4.z * w4.z), (bf16)(g4.w * w4.w) };
  ((bf16x4*)(W2p + (size_t)n * 1024))[tid] = o;
  float s = (float)o[0] + (float)o[1] + (float)o[2] + (float)o[3];
  float cbv = b4.x * w4.x + b4.y * w4.y + b4.z * w4.z + b4.w * w4.w;
#pragma unroll
  for (int off = 1; off < 64; off <<= 1) {
    s += __shfl_xor(s, off);
    cbv += __shfl_xor(cbv, off);
  }
  __shared__ float rs_[4], rc_[4];
  if ((tid & 63) == 0) { rs_[tid >> 6] = s; rc_[tid >> 6] = cbv; }
  __syncthreads();
  if (tid == 0) {
    csum[n] = rs_[0] + rs_[1] + rs_[2] + rs_[3];
    cbias[n] = rc_[0] + rc_[1] + rc_[2] + rc_[3] + bin2[n];
  }
}

// ---- in_proj GEMM (layer 1): writes bf16 uv PLANES ----
__global__ __launch_bounds__(256) void gemm_uv(const bf16* __restrict__ A,
                                               const bf16* __restrict__ Bw,
                                               const float* __restrict__ bias,
                                               bf16* __restrict__ uvp,
                                               int M, int N, int K) {
  __shared__ bf16 As[128 * 32];
  __shared__ bf16 Bs[128 * 32];
  const int tid = threadIdx.x;
  const int lane = tid & 63;
  const int wave = tid >> 6;
  const int m0 = blockIdx.y * 128;
  const int n0 = blockIdx.x * 128;
  const int wm = (wave >> 1) * 64;
  const int wn = (wave & 1) * 64;
  f32x4 acc[4][4] = {};

  for (int kt = 0; kt < K; kt += 32) {
#pragma unroll
    for (int it = 0; it < 2; ++it) {
      const int gidx = it * 256 + tid;
      const int row = gidx >> 2;
      const int col = (gidx & 3) << 3;
      __builtin_amdgcn_global_load_lds(AS1C(A + (size_t)(m0 + row) * K + kt + col),
                                       AS3(&As[gidx * 8]), 16, 0, 0);
      __builtin_amdgcn_global_load_lds(AS1C(Bw + (size_t)(n0 + row) * K + kt + col),
                                       AS3(&Bs[gidx * 8]), 16, 0, 0);
    }
    __syncthreads();
    bf16x8 af[4], bfr[4];
#pragma unroll
    for (int i = 0; i < 4; ++i)
      af[i] = *(const bf16x8*)&As[(wm + i * 16 + (lane & 15)) * 32 + (lane >> 4) * 8];
#pragma unroll
    for (int j = 0; j < 4; ++j)
      bfr[j] = *(const bf16x8*)&Bs[(wn + j * 16 + (lane & 15)) * 32 + (lane >> 4) * 8];
#pragma unroll
    for (int i = 0; i < 4; ++i)
#pragma unroll
      for (int j = 0; j < 4; ++j)
        acc[i][j] = __builtin_amdgcn_mfma_f32_16x16x32_bf16(af[i], bfr[j], acc[i][j], 0, 0, 0);
    __syncthreads();
  }

  const int cr = (lane >> 4) * 4;
  const int cc = lane & 15;
#pragma unroll
  for (int i = 0; i < 4; ++i) {
#pragma unroll
    for (int j = 0; j < 4; ++j) {
      const int mb = m0 + wm + i * 16 + cr;
      const int n = n0 + wn + j * 16 + cc;
      const float bn = bias[n];
      const int p = n >> 10;
      const int nn2 = n & 1023;
#pragma unroll
      for (int r = 0; r < 4; ++r) {
        const int row = mb + r;
        const int b = row >> 11;
        const int t = row & (T_ - 1);
        uvp[(size_t)p * T_ * 8192 + (size_t)t * 8192 + nn2 * 8 + b] =
            (bf16)(acc[i][j][r] + bn);
      }
    }
  }
}

// ---- final out_proj GEMM (layer 2): A from H2 frames, resid from out1F frames --
__global__ __launch_bounds__(256) void gemm_hfrag(const char* __restrict__ Hb,
                                                  const bf16* __restrict__ Bw,
                                                  const float* __restrict__ bias,
                                                  const char* __restrict__ residF,
                                                  float* __restrict__ C,
                                                  int M, int N, int K) {
  __shared__ bf16 As[128 * 32];
  __shared__ bf16 Bs[128 * 32];
  const int tid = threadIdx.x;
  const int lane = tid & 63;
  const int wave = tid >> 6;
  const int m0 = blockIdx.y * 128;
  const int n0 = blockIdx.x * 128;
  const int wm = (wave >> 1) * 64;
  const int wn = (wave & 1) * 64;
  f32x4 acc[4][4] = {};

  for (int kt = 0; kt < K; kt += 32) {
#pragma unroll
    for (int it = 0; it < 2; ++it) {
      const int g = it * 256 + tid;
      const int r = g >> 2;
      const int sub = g & 3;
      const int R = m0 + r;
      const int bb = R >> 11;
      const int tt = R & (T_ - 1);
      const char* src = Hb + (size_t)tt * 16384 + (size_t)(kt >> 5) * 512
                        + (sub * 8 + bb) * 16;
      __builtin_amdgcn_global_load_lds(AS1C(src), AS3(&As[g * 8]), 16, 0, 0);
      __builtin_amdgcn_global_load_lds(AS1C(Bw + (size_t)(n0 + r) * K + kt + (sub << 3)),
                                       AS3(&Bs[g * 8]), 16, 0, 0);
    }
    __syncthreads();
    bf16x8 af[4], bfr[4];
#pragma unroll
    for (int i = 0; i < 4; ++i)
      af[i] = *(const bf16x8*)&As[(wm + i * 16 + (lane & 15)) * 32 + (lane >> 4) * 8];
#pragma unroll
    for (int j = 0; j < 4; ++j)
      bfr[j] = *(const bf16x8*)&Bs[(wn + j * 16 + (lane & 15)) * 32 + (lane >> 4) * 8];
#pragma unroll
    for (int i = 0; i < 4; ++i)
#pragma unroll
      for (int j = 0; j < 4; ++j)
        acc[i][j] = __builtin_amdgcn_mfma_f32_16x16x32_bf16(af[i], bfr[j], acc[i][j], 0, 0, 0);
    __syncthreads();
  }

  const int cr = (lane >> 4) * 4;
  const int cc = lane & 15;
#pragma unroll
  for (int i = 0; i < 4; ++i) {
#pragma unroll
    for (int j = 0; j < 4; ++j) {
      const int mb = m0 + wm + i * 16 + cr;
      const int n = n0 + wn + j * 16 + cc;
      const float bn = bias[n];
      const int foffn = (n >> 5) * 512 + (((n & 31) >> 3) * 8) * 16 + (n & 7) * 2;
#pragma unroll
      for (int r = 0; r < 4; ++r) {
        const int row = mb + r;
        const int b = row >> 11;
        const int tt2 = row & (T_ - 1);
        const float resid =
            (float)*(const bf16*)(residF + (size_t)tt2 * 16384 + foffn + b * 16);
        C[(size_t)row * N + n] = acc[i][j][r] + bn + resid;
      }
    }
  }
}

// ================= mega persistent pipeline =================
__device__ __forceinline__ void load_wb(bf16x8 (&wB)[32], const bf16* Wrow) {
  const int half = ((threadIdx.x & 63) >> 4) << 3;
#pragma unroll
  for (int kk = 0; kk < 32; ++kk)
    wB[kk] = *(const bf16x8*)(Wrow + kk * 32 + half);
#pragma unroll
  for (int kk = 0; kk < 32; ++kk)
    asm volatile("" : "+a"(wB[kk]));  // park in AGPRs
}

__device__ __forceinline__ f32x4 frag_matvec(const char* __restrict__ dF, int rdoff,
                                             const bf16x8 (&wB)[32]) {
  f32x4 a0 = {0.f, 0.f, 0.f, 0.f}, a1 = a0, a2 = a0, a3 = a0;
#pragma unroll
  for (int kk = 0; kk < 32; kk += 4) {
    bf16x8 f0 = *(const bf16x8*)(dF + kk * 512 + rdoff);
    bf16x8 f1 = *(const bf16x8*)(dF + (kk + 1) * 512 + rdoff);
    bf16x8 f2 = *(const bf16x8*)(dF + (kk + 2) * 512 + rdoff);
    bf16x8 f3 = *(const bf16x8*)(dF + (kk + 3) * 512 + rdoff);
    a0 = __builtin_amdgcn_mfma_f32_16x16x32_bf16(f0, wB[kk], a0, 0, 0, 0);
    a1 = __builtin_amdgcn_mfma_f32_16x16x32_bf16(f1, wB[kk + 1], a1, 0, 0, 0);
    a2 = __builtin_amdgcn_mfma_f32_16x16x32_bf16(f2, wB[kk + 2], a2, 0, 0, 0);
    a3 = __builtin_amdgcn_mfma_f32_16x16x32_bf16(f3, wB[kk + 3], a3, 0, 0, 0);
  }
  return (a0 + a1) + (a2 + a3);
}

template <int SLP>
__device__ __forceinline__ void poll8(const unsigned* base, unsigned tgt) {
  const int lane = threadIdx.x & 63;
  unsigned sv = tgt;
  if (lane < 8)
    sv = __hip_atomic_load(base + lane * 16, __ATOMIC_RELAXED, __HIP_MEMORY_SCOPE_AGENT);
  while (!__all((int)(sv >= tgt))) {
    __builtin_amdgcn_s_sleep(SLP);
    if (lane < 8)
      sv = __hip_atomic_load(base + lane * 16, __ATOMIC_RELAXED, __HIP_MEMORY_SCOPE_AGENT);
  }
  (void)__hip_atomic_load(base, __ATOMIC_ACQUIRE, __HIP_MEMORY_SCOPE_AGENT);
}

// Combined poll (r14): lanes 0-7 check own gang slots vs tOwn; lanes 8-9 check
// the two S3 producer slots vs tGate. tGate==0 -> lanes 8-9 read the own-base
// line instead (no hot-gate-line traffic on non-check steps).
template <bool GATED>
__device__ __forceinline__ void poll_comb(const unsigned* sync, int ownBase, int wg,
                                          unsigned tOwn, unsigned tGate) {
  const int lane = threadIdx.x & 63;
  const unsigned* addr = sync + ownBase;
  unsigned tgt = 0u;
  if (lane < 8) { addr = sync + ownBase + lane * 16; tgt = tOwn; }
  else if (GATED && lane < 10 && tGate > 0) {
    addr = sync + 256 + ((lane == 9 ? 8 : 0) + wg) * 16;
    tgt = tGate;
  }
  unsigned sv = __hip_atomic_load(addr, __ATOMIC_RELAXED, __HIP_MEMORY_SCOPE_AGENT);
  while (!__all((int)(sv >= tgt))) {
    __builtin_amdgcn_s_sleep(1);
    sv = __hip_atomic_load(addr, __ATOMIC_RELAXED, __HIP_MEMORY_SCOPE_AGENT);
  }
  (void)__hip_atomic_load(sync + ownBase, __ATOMIC_ACQUIRE, __HIP_MEMORY_SCOPE_AGENT);
}

__device__ __forceinline__ void stage16k(const char* srcF, char* dstF, int tid) {
  __builtin_amdgcn_global_load_lds(AS1C(srcF + tid * 16), AS3(dstF + tid * 16), 16, 0, 0);
  __builtin_amdgcn_global_load_lds(AS1C(srcF + (512 + tid) * 16),
                                   AS3(dstF + (512 + tid) * 16), 16, 0, 0);
}

// Scans (r14 + amortized gate): uv prefetched one step ahead AFTER the release.
// GATED (S4): gate checked only at t%8==1 demanding min(t+15,T) — strictly
// stronger than r14's every-step t+8, with 1/8 the hot-gate-line reads.
template <bool GATED>
__device__ __forceinline__ void scan_gang(int wg, const bf16* uvU, const bf16* uvV,
    const bf16* Wh, const float* bh, char* Hb, unsigned* sync, int ownBase,
    char (*hC)[16384], char (*tscr)[256]) {
  const int tid = threadIdx.x;
  const int lane = tid & 63;
  const int wv = tid >> 6;
  const int Wg = wg * 8 + wv;
  const int n0 = Wg * 16;
  const int c = lane & 15;

  bf16x8 wB[32];
  load_wb(wB, Wh + ((size_t)(n0 + c) << 10));

  const float bh_n = bh[n0 + c];
  const int b0 = (lane >> 4) * 4;
  const int rdoff = ((lane >> 4) * 8 + (lane & 7)) * 16;
  const int wregion = Wg * 256;

  float hs0 = 0.f, hs1 = 0.f, hs2 = 0.f, hs3 = 0.f;
  bf16x4 uq = {}, vq = {};

  // initial gate (S3 >= 16 steps done) + uv[0] prefetch
  if (GATED) poll_comb<true>(sync, ownBase, wg, 0u, (unsigned)(16 < T_ ? 16 : T_));
  if (lane < 32) {
    uq = *(const bf16x4*)(uvU + (n0 + c) * 8 + b0);
    vq = *(const bf16x4*)(uvV + (n0 + c) * 8 + b0);
  }

  for (int t = 0; t < T_; ++t) {
    f32x4 asum = {0.f, 0.f, 0.f, 0.f};
    if (t > 0) {
      const unsigned g = (GATED && (t & 7) == 1)
                             ? (unsigned)((t + 15 < T_) ? t + 15 : T_) : 0u;
      poll_comb<GATED>(sync, ownBase, wg, (unsigned)t, g);
      __builtin_amdgcn_sched_barrier(0);
      stage16k(Hb + (size_t)(t - 1) * 16384, hC[t & 1], tid);
      __syncthreads();
      asum = frag_matvec(hC[t & 1], rdoff, wB);
    }

    char* wscr = tscr[wv];
    if (lane < 32) {
#pragma unroll
      for (int r = 0; r < 4; ++r) {
        const float uu = (float)uq[r];
        const float vv = (float)vq[r];
        float& hh = (r == 0) ? hs0 : (r == 1) ? hs1 : (r == 2) ? hs2 : hs3;
        const float s = asum[r] + bh_n + vv;
        const float gg = __builtin_amdgcn_rcpf(1.f + __expf(-uu));
        const float e = __expf(2.f * s);
        const float cand = 1.f - 2.f * __builtin_amdgcn_rcpf(e + 1.f);
        hh = fmaf(gg, cand - hh, hh);
        *(bf16*)(wscr + (c >> 3) * 128 + (b0 + r) * 16 + (c & 7) * 2) = (bf16)hh;
      }
    }
    asm volatile("s_waitcnt lgkmcnt(0)" ::: "memory");
    __builtin_amdgcn_sched_barrier(0);
    if (lane < 32) {
      const unsigned long long pv = *(const unsigned long long*)(wscr + lane * 8);
      char* dst = Hb + (size_t)t * 16384 + wregion + lane * 8;
      __hip_atomic_store((unsigned long long*)dst, pv,
                         __ATOMIC_RELAXED, __HIP_MEMORY_SCOPE_AGENT);
    }
    __syncthreads();
    if (tid == 0)
      __hip_atomic_store(sync + ownBase + wg * 16, (unsigned)(t + 1),
                         __ATOMIC_RELEASE, __HIP_MEMORY_SCOPE_AGENT);
    __builtin_amdgcn_sched_barrier(0);
    // uv prefetch for t+1, post-release (gate guarantee covers GATED reads:
    // last check at t0>=t-6 demanded t0+15 >= t+9 > t+2).
    if (t < T_ - 1 && lane < 32) {
      uq = *(const bf16x4*)(uvU + (size_t)(t + 1) * 8192 + (n0 + c) * 8 + b0);
      vq = *(const bf16x4*)(uvV + (size_t)(t + 1) * 8192 + (n0 + c) * 8 + b0);
    }
  }
}

// S2: out1[t] = x[t] + h1[t] @ Wout1^T + bout1  (pipelined stage, no recurrence)
__device__ __forceinline__ void s2_gang(int wg, const char* H1, const bf16* Wout,
    const float* bout, const float* x, char* out1F, unsigned* sync,
    char (*hC)[16384], char (*tscr)[256]) {
  const int tid = threadIdx.x;
  const int lane = tid & 63;
  const int wv = tid >> 6;
  const int W2 = wg * 8 + wv;
  const int n0 = W2 * 16;
  const int c = lane & 15;

  bf16x8 wB[32];
  load_wb(wB, Wout + ((size_t)(n0 + c) << 10));

  const float bo = bout[n0 + c];
  const int b0 = (lane >> 4) * 4;
  const int rdoff = ((lane >> 4) * 8 + (lane & 7)) * 16;
  const int wregion = W2 * 256;

  f32x4 xq = {0.f, 0.f, 0.f, 0.f};
  if (lane < 32) {
#pragma unroll
    for (int r = 0; r < 4; ++r)
      xq[r] = x[((size_t)(b0 + r) * T_) * 1024 + n0 + c];
  }

  poll8<4>(sync, 1u);
  __builtin_amdgcn_sched_barrier(0);
  stage16k(H1, hC[0], tid);

  for (int t = 0; t < T_; ++t) {
    __syncthreads();  // stage t complete
    f32x4 asum = frag_matvec(hC[t & 1], rdoff, wB);

    char* wscr = tscr[wv];
    if (lane < 32) {
#pragma unroll
      for (int r = 0; r < 4; ++r) {
        const float o = xq[r] + asum[r] + bo;
        *(bf16*)(wscr + (c >> 3) * 128 + (b0 + r) * 16 + (c & 7) * 2) = (bf16)o;
      }
    }
    asm volatile("s_waitcnt lgkmcnt(0)" ::: "memory");
    __builtin_amdgcn_sched_barrier(0);
    if (lane < 32) {
      const unsigned long long pv = *(const unsigned long long*)(wscr + lane * 8);
      char* dst = out1F + (size_t)t * 16384 + wregion + lane * 8;
      __hip_atomic_store((unsigned long long*)dst, pv,
                         __ATOMIC_RELAXED, __HIP_MEMORY_SCOPE_AGENT);
    }
    __syncthreads();
    if (tid == 0)
      __hip_atomic_store(sync + 128 + wg * 16, (unsigned)(t + 1),
                         __ATOMIC_RELEASE, __HIP_MEMORY_SCOPE_AGENT);
    __builtin_amdgcn_sched_barrier(0);
    if (t + 1 < T_) {
      poll8<4>(sync, (unsigned)(t + 2));
      __builtin_amdgcn_sched_barrier(0);
      stage16k(H1 + (size_t)(t + 1) * 16384, hC[(t + 1) & 1], tid);
      if (lane < 32) {
#pragma unroll
        for (int r = 0; r < 4; ++r)
          xq[r] = x[((size_t)(b0 + r) * T_ + (t + 1)) * 1024 + n0 + c];
      }
    }
  }
}

// S3: uv2[t] = folded-LN(out1[t]) @ W2p^T  (pipelined stage + conflict-free stats)
__device__ __forceinline__ void s3_gang(int wg, const char* out1F, const bf16* W2p,
    const float* csum2, const float* cbias2, bf16* uv2, unsigned* sync,
    char (*hC)[16384], char (*tscr)[256], float* statp) {
  const int tid = threadIdx.x;
  const int lane = tid & 63;
  const int wv = tid >> 6;
  const int W3 = wg * 8 + wv;              // 0..127
  const int c = lane & 15;
  const int n = W3 * 16 + c;               // col in [0,2048)

  bf16x8 wB[32];
  load_wb(wB, W2p + ((size_t)n << 10));

  const float cs = csum2[n];
  const float cb = cbias2[n];
  const int b0 = (lane >> 4) * 4;
  const int rdoff = ((lane >> 4) * 8 + (lane & 7)) * 16;
  char* outPlane = (char*)(uv2 + (size_t)(W3 >> 6) * T_ * 8192);
  const int nn = (W3 & 63) * 16;
  const int sidx = wv * 128 + lane;        // contiguous 16B block index

  poll8<4>(sync + 128, 1u);
  __builtin_amdgcn_sched_barrier(0);
  stage16k(out1F, hC[0], tid);

  for (int t = 0; t < T_; ++t) {
    __syncthreads();  // stage t complete
    const char* dstF = hC[t & 1];
    // LN stats partials: contiguous reads (conflict-free); block%8 == batch
    {
      bf16x8 v0 = *(const bf16x8*)(dstF + sidx * 16);
      bf16x8 v1 = *(const bf16x8*)(dstF + sidx * 16 + 1024);
      float s1 = 0.f, s2 = 0.f;
#pragma unroll
      for (int j = 0; j < 8; ++j) {
        const float f0 = (float)v0[j], f1 = (float)v1[j];
        s1 += f0 + f1;
        s2 += f0 * f0 + f1 * f1;
      }
#pragma unroll
      for (int off = 8; off < 64; off <<= 1) {
        s1 += __shfl_xor(s1, off);
        s2 += __shfl_xor(s2, off);
      }
      if (lane < 8) {
        statp[(wv * 8 + lane) * 2] = s1;
        statp[(wv * 8 + lane) * 2 + 1] = s2;
      }
    }
    f32x4 asum = frag_matvec(dstF, rdoff, wB);
    __syncthreads();  // statp ready
    char* wscr = tscr[wv];
    if (lane < 32) {
#pragma unroll
      for (int r = 0; r < 4; ++r) {
        const int b = b0 + r;
        float s1 = 0.f, s2 = 0.f;
#pragma unroll
        for (int w = 0; w < 8; ++w) {
          s1 += statp[(w * 8 + b) * 2];
          s2 += statp[(w * 8 + b) * 2 + 1];
        }
        const float mu = s1 * (1.f / 1024.f);
        const float var = s2 * (1.f / 1024.f) - mu * mu;
        const float rs = rsqrtf(var + 1e-5f);
        const float val = rs * (asum[r] - mu * cs) + cb;
        *(bf16*)(wscr + c * 16 + b * 2) = (bf16)val;
      }
    }
    asm volatile("s_waitcnt lgkmcnt(0)" ::: "memory");
    __builtin_amdgcn_sched_barrier(0);
    if (lane < 32) {
      const unsigned long long pv = *(const unsigned long long*)(wscr + lane * 8);
      char* dst = outPlane + (size_t)t * 16384 + nn * 16 + lane * 8;
      __hip_atomic_store((unsigned long long*)dst, pv,
                         __ATOMIC_RELAXED, __HIP_MEMORY_SCOPE_AGENT);
    }
    __syncthreads();
    if (tid == 0)
      __hip_atomic_store(sync + 256 + wg * 16, (unsigned)(t + 1),
                         __ATOMIC_RELEASE, __HIP_MEMORY_SCOPE_AGENT);
    __builtin_amdgcn_sched_barrier(0);
    if (t + 1 < T_) {
      poll8<4>(sync + 128, (unsigned)(t + 2));
      __builtin_amdgcn_sched_barrier(0);
      stage16k(out1F + (size_t)(t + 1) * 16384, hC[(t + 1) & 1], tid);
    }
  }
}

__global__ __launch_bounds__(512, 1) void mega_kernel(
    const bf16* __restrict__ uv1, const bf16* __restrict__ Wh,
    const float* __restrict__ bh, const bf16* __restrict__ Wout,
    const float* __restrict__ bout, const float* __restrict__ x,
    const bf16* __restrict__ W2p, const float* __restrict__ csum2,
    const float* __restrict__ cbias2, char* __restrict__ H1,
    char* __restrict__ out1F, bf16* __restrict__ uv2, char* __restrict__ H2,
    unsigned* __restrict__ sync) {
  __shared__ __align__(16) char hC[2][16384];
  __shared__ __align__(16) char tscr[8][256];
  __shared__ float statp[128];
  const int bid = blockIdx.x;
  if (bid < 8) {
    scan_gang<false>(bid, uv1, uv1 + (size_t)T_ * 8192, Wh, bh, H1, sync, 0, hC, tscr);
  } else if (bid < 16) {
    s2_gang(bid - 8, H1, Wout, bout, x, out1F, sync, hC, tscr);
  } else if (bid < 32) {
    s3_gang(bid - 16, out1F, W2p, csum2, cbias2, uv2, sync, hC, tscr, statp);
  } else {
    scan_gang<true>(bid - 32, uv2, uv2 + (size_t)T_ * 8192,
                    Wh + (size_t)D_ * D_, bh + D_, H2, sync, 512, hC, tscr);
  }
}

extern "C" void kernel_launch(void* const* d_in, const int* in_sizes, int n_in,
                              void* d_out, int out_size, void* d_ws, size_t ws_size,
                              hipStream_t stream) {
  const float* x     = (const float*)d_in[0];
  const float* ln_g  = (const float*)d_in[1];
  const float* ln_b  = (const float*)d_in[2];
  const float* W_in  = (const float*)d_in[3];
  const float* b_in  = (const float*)d_in[4];
  const float* W_h   = (const float*)d_in[5];
  const float* b_h   = (const float*)d_in[6];
  const float* W_out = (const float*)d_in[7];
  const float* b_out = (const float*)d_in[8];
  float* out = (float*)d_out;

  char* ws = (char*)d_ws;
  size_t off = 0;
  auto alloc = [&](size_t bytes) -> void* {
    void* p = ws + off;
    off = (off + bytes + 255) & ~(size_t)255;
    return p;
  };
  bf16* wInB   = (bf16*)alloc((size_t)L_ * 2 * D_ * D_ * 2);   // 8 MB
  bf16* wHB    = (bf16*)alloc((size_t)L_ * D_ * D_ * 2);       // 4 MB
  bf16* wOutB  = (bf16*)alloc((size_t)L_ * D_ * D_ * 2);       // 4 MB
  bf16* W2p    = (bf16*)alloc((size_t)2 * D_ * D_ * 2);        // 4 MB
  float* csum2 = (float*)alloc(2 * D_ * 4);
  float* cbias2= (float*)alloc(2 * D_ * 4);
  bf16* Xn     = (bf16*)alloc((size_t)B_ * T_ * D_ * 2);       // 32 MB (reused as H2)
  char* H2     = (char*)Xn;
  bf16* uvp1   = (bf16*)alloc((size_t)2 * T_ * 8192 * 2);      // 64 MB
  char* H1     = (char*)alloc((size_t)T_ * 16384);             // 32 MB
  char* out1F  = (char*)alloc((size_t)T_ * 16384);             // 32 MB
  bf16* uvp2   = (bf16*)alloc((size_t)2 * T_ * 8192 * 2);      // 64 MB
  unsigned* sync = (unsigned*)alloc(4096);
  (void)ws_size; (void)in_sizes; (void)n_in; (void)out_size;   // ~244 MB used

  {
    int n4 = L_ * 2 * D_ * D_ / 4;
    cvt_kernel<<<(n4 + 255) / 256, 256, 0, stream>>>(W_in, wInB, n4);
    n4 = L_ * D_ * D_ / 4;
    cvt_kernel<<<(n4 + 255) / 256, 256, 0, stream>>>(W_h, wHB, n4);
    cvt_kernel<<<(n4 + 255) / 256, 256, 0, stream>>>(W_out, wOutB, n4);
  }
  prep2_kernel<<<2 * D_, 256, 0, stream>>>(W_in + (size_t)2 * D_ * D_,
                                           ln_g + D_, ln_b + D_, b_in + 2 * D_,
                                           W2p, csum2, cbias2);

  const int Mrows = B_ * T_;  // 16384
  ln_kernel<<<Mrows, 256, 0, stream>>>(x, ln_g, ln_b, Xn);

  dim3 g1(2 * D_ / 128, Mrows / 128);
  gemm_uv<<<g1, 256, 0, stream>>>(Xn, wInB, b_in, uvp1, Mrows, 2 * D_, D_);

  (void)hipMemsetAsync(sync, 0, 4096, stream);
  mega_kernel<<<40, 512, 0, stream>>>(uvp1, wHB, b_h, wOutB, b_out, x,
                                      W2p, csum2, cbias2, H1, out1F, uvp2, H2, sync);

  dim3 g2(D_ / 128, Mrows / 128);
  gemm_hfrag<<<g2, 256, 0, stream>>>(H2, wOutB + (size_t)D_ * D_, b_out + D_,
                                     out1F, out, Mrows, D_, D_);
}